// Round 14
// baseline (536.782 us; speedup 1.0000x reference)
//
#include <hip/hip_runtime.h>
#include <cstdint>
#include <cstddef>

#define B_  2
#define S_  2048
#define H_  768
#define NH  12
#define DH  64
#define RD  5
#define BN  (B_*NH)   // 24

typedef _Float16 f16;
typedef __attribute__((ext_vector_type(8))) _Float16 f16x8;
typedef __attribute__((ext_vector_type(4))) float f32x4;

#define MFMA16(a, b, c) __builtin_amdgcn_mfma_f32_16x16x32_f16((a), (b), (c), 0, 0, 0)

#if __has_builtin(__builtin_amdgcn_exp2f)
__device__ __forceinline__ float exp2fast(float x) { return __builtin_amdgcn_exp2f(x); }
#else
__device__ __forceinline__ float exp2fast(float x) { return __expf(0.69314718056f * x); }
#endif

#define SCL 0.1803368801f   /* 0.125 * log2(e) */
#define L2E 1.44269504f

// fp32 -> f16 convert-and-store of 16 contiguous elements.
__device__ __forceinline__ void cvt16(const float* __restrict__ src, f16* dst)
{
    float4 f0 = ((const float4*)src)[0];
    float4 f1 = ((const float4*)src)[1];
    float4 f2 = ((const float4*)src)[2];
    float4 f3 = ((const float4*)src)[3];
    f16 h[16] = {(f16)f0.x, (f16)f0.y, (f16)f0.z, (f16)f0.w,
                 (f16)f1.x, (f16)f1.y, (f16)f1.z, (f16)f1.w,
                 (f16)f2.x, (f16)f2.y, (f16)f2.z, (f16)f2.w,
                 (f16)f3.x, (f16)f3.y, (f16)f3.z, (f16)f3.w};
    *(f16x8*)dst       = *(const f16x8*)&h[0];
    *(f16x8*)(dst + 8) = *(const f16x8*)&h[8];
}

// ---------------------------------------------------------------------------
// Kernel 1 (FUSED): qkv_gemm (fp32 inputs, in-staging f16 convert) + adjpack.
// Verified round 9/13: 480 us pipeline.
// ---------------------------------------------------------------------------
__global__ __launch_bounds__(256, 3) void qkv_pack(
    const float* __restrict__ hs,
    const float* __restrict__ Wq, const float* __restrict__ Wk,
    const float* __restrict__ Wv,
    const float* __restrict__ bq, const float* __restrict__ bk,
    const float* __restrict__ bv,
    f16* __restrict__ qo, f16* __restrict__ ko, f16* __restrict__ vt,
    const float* __restrict__ adj, unsigned char* __restrict__ adjp)
{
    __shared__ __align__(16) f16 Xs[64][72];
    __shared__ __align__(16) f16 Ws[3][64][72];

    const int tid = threadIdx.x;

    if (blockIdx.x >= 768) {
        const int idx4 = (blockIdx.x - 768) * 256 + tid;   // [0, 2^19)
        const int j4 = idx4 & 511;
        const int iq = (idx4 >> 9) & 511;
        const int b  = idx4 >> 18;
        unsigned int wbits[4] = {0, 0, 0, 0};
#pragma unroll
        for (int r = 0; r < RD; ++r) {
#pragma unroll
            for (int ii = 0; ii < 4; ++ii) {
                float4 v = *(const float4*)(adj +
                    (((size_t)(r * B_ + b) * S_) + iq * 4 + ii) * S_ + j4 * 4);
                float vv[4] = {v.x, v.y, v.z, v.w};
#pragma unroll
                for (int jj = 0; jj < 4; ++jj)
                    wbits[jj] |= (vv[jj] != 0.f ? 1u : 0u) << (r + 8 * ii);
            }
        }
        uint4 pk = {wbits[0], wbits[1], wbits[2], wbits[3]};
        *(uint4*)(adjp + ((size_t)(b * 512 + iq) * S_ + j4 * 4) * 4) = pk;
        return;
    }

    const int n  = blockIdx.x % 12;
    const int m0 = (blockIdx.x / 12) * 64;
    const int w = tid >> 6, lane = tid & 63;
    const int l15 = lane & 15, quad = lane >> 4;
    const int srow = tid >> 2, sc0 = (tid & 3) * 16;

    f32x4 acc[3][4];
#pragma unroll
    for (int i = 0; i < 3; ++i)
#pragma unroll
        for (int ns = 0; ns < 4; ++ns) acc[i][ns] = (f32x4){0.f, 0.f, 0.f, 0.f};

    const float* xsrc = hs + (size_t)(m0 + srow) * H_ + sc0;
    const float* w0src = Wq + (size_t)(n * 64 + srow) * H_ + sc0;
    const float* w1src = Wk + (size_t)(n * 64 + srow) * H_ + sc0;
    const float* w2src = Wv + (size_t)(n * 64 + srow) * H_ + sc0;

    for (int kc = 0; kc < 12; ++kc) {
        __syncthreads();
        cvt16(xsrc  + kc * 64, &Xs[srow][sc0]);
        cvt16(w0src + kc * 64, &Ws[0][srow][sc0]);
        cvt16(w1src + kc * 64, &Ws[1][srow][sc0]);
        cvt16(w2src + kc * 64, &Ws[2][srow][sc0]);
        __syncthreads();

        f16x8 a0 = *(const f16x8*)&Xs[w * 16 + l15][quad * 8];
        f16x8 a1 = *(const f16x8*)&Xs[w * 16 + l15][quad * 8 + 32];
#pragma unroll
        for (int i = 0; i < 3; ++i)
#pragma unroll
            for (int ns = 0; ns < 4; ++ns) {
                f16x8 b0 = *(const f16x8*)&Ws[i][ns * 16 + l15][quad * 8];
                f16x8 b1 = *(const f16x8*)&Ws[i][ns * 16 + l15][quad * 8 + 32];
                acc[i][ns] = MFMA16(a0, b0, acc[i][ns]);
                acc[i][ns] = MFMA16(a1, b1, acc[i][ns]);
            }
    }
    __syncthreads();

    const float* bias[3] = {bq, bk, bv};
    f16 (*T0)[72] = Xs;      // q
    f16 (*T1)[72] = Ws[0];   // k
    f16 (*T2)[72] = Ws[1];   // v
#pragma unroll
    for (int i = 0; i < 3; ++i) {
        f16 (*T)[72] = (i == 0) ? T0 : (i == 1) ? T1 : T2;
#pragma unroll
        for (int ns = 0; ns < 4; ++ns) {
            float bb = bias[i][n * 64 + ns * 16 + l15];
#pragma unroll
            for (int reg = 0; reg < 4; ++reg)
                T[w * 16 + quad * 4 + reg][ns * 16 + l15] =
                    (f16)(acc[i][ns][reg] + bb);
        }
    }
    __syncthreads();

    const int mrow = m0 + srow;
    const int bb2 = mrow >> 11, ss = mrow & 2047;
    {
        f16* dst = qo + ((size_t)(bb2 * NH + n) * S_ + ss) * DH + sc0;
        *(f16x8*)dst       = *(const f16x8*)&T0[srow][sc0];
        *(f16x8*)(dst + 8) = *(const f16x8*)&T0[srow][sc0 + 8];
    }
    {
        f16* dst = ko + ((size_t)(bb2 * NH + n) * S_ + ss) * DH + sc0;
        *(f16x8*)dst       = *(const f16x8*)&T1[srow][sc0];
        *(f16x8*)(dst + 8) = *(const f16x8*)&T1[srow][sc0 + 8];
    }
    {
        f16 tmp[16];
#pragma unroll
        for (int u = 0; u < 16; ++u) tmp[u] = T2[sc0 + u][srow];
        f16* dst = vt + ((size_t)(bb2 * NH + n) * DH + srow) * S_ + (m0 & 2047) + sc0;
        *(f16x8*)dst       = *(const f16x8*)&tmp[0];
        *(f16x8*)(dst + 8) = *(const f16x8*)&tmp[8];
    }
}

// ---------------------------------------------------------------------------
// Kernel 2: MFMA flash attention -- round-13 verified body (215 us) with ONE
// change: t-loop "#pragma unroll 1" -> "#pragma unroll 2".  Rationale: all
// MANUAL cross-tile pipelining failed on forced double-buffer register
// demotion (rounds 4/5); but the compiler was never ALLOWED to pipeline
// across tiles (unroll 1 forbids interleaving SCORES(t+1) -- 48 independent
// MFMAs -- with softmax/PV(t)).  The compiler renames only where registers
// are free; unroll 2 grants it the freedom without forcing extra state.
// Pre-committed readings: pipelined (MfmaUtil up, attn ~190) / spilled
// (WRITE balloons -> revert) / neutral (identical codegen, zero loss).
// ---------------------------------------------------------------------------
__global__ __launch_bounds__(256, 3) void attn(
    const f16* __restrict__ q, const f16* __restrict__ k, const f16* __restrict__ vt,
    const float* __restrict__ bili, const unsigned char* __restrict__ adjp,
    const float* __restrict__ mask, const float* __restrict__ absb,
    float* __restrict__ out)
{
    __shared__ __align__(16) char smem[9216 + 9216 + 128];
    f16*   Mt  = (f16*)smem;                    // [64][72] (prologue only)
    f16*   Pb  = (f16*)(smem + 9216);           // [4][16][72]
    float* lut = (float*)(smem + 9216 + 9216);  // [32]

    const int tid = threadIdx.x;
    const int idx = blockIdx.x;
    const int g = idx & 7;
    const int it = (idx >> 3) & 31;
    const int bn = 8 * (idx >> 8) + g;
    const int b = bn / NH, n = bn % NH;
    const int w = tid >> 6, lane = tid & 63;
    const int l15 = lane & 15, quad = lane >> 4;
    const int wi0 = it * 64 + w * 16;
    const size_t kbase = (size_t)bn * S_ * DH;

    if (tid < 32) {
        float a = 0.f;
#pragma unroll
        for (int r = 0; r < RD; ++r)
            if (tid & (1 << r)) a += absb[r * NH + n];
        lut[tid] = a * SCL;
    }

    const f16* qrow = q + kbase + (size_t)(wi0 + l15) * DH + quad * 8;
    f16x8 aq0 = *(const f16x8*)(qrow);
    f16x8 aq1 = *(const f16x8*)(qrow + 32);

    f16* Pw = Pb + w * 16 * 72;

    // ---- build Q'_r A-frags via MFMA (M_r staged transposed in LDS) ----
    f16x8 aqp[RD][2];
#pragma unroll
    for (int r = 0; r < RD; ++r) {
        __syncthreads();
        {
            int p = tid >> 2, q0 = (tid & 3) * 16;
            const float* src = bili + ((size_t)(r * NH + n) * DH + p) * DH + q0;
            float4 g0 = ((const float4*)src)[0];
            float4 g1 = ((const float4*)src)[1];
            float4 g2 = ((const float4*)src)[2];
            float4 g3 = ((const float4*)src)[3];
            float mv[16] = {g0.x, g0.y, g0.z, g0.w, g1.x, g1.y, g1.z, g1.w,
                            g2.x, g2.y, g2.z, g2.w, g3.x, g3.y, g3.z, g3.w};
#pragma unroll
            for (int u = 0; u < 16; ++u) Mt[(q0 + u) * 72 + p] = (f16)mv[u];
        }
        __syncthreads();
#pragma unroll
        for (int ns = 0; ns < 4; ++ns) {
            f16x8 b0 = *(const f16x8*)&Mt[(ns * 16 + l15) * 72 + quad * 8];
            f16x8 b1 = *(const f16x8*)&Mt[(ns * 16 + l15) * 72 + quad * 8 + 32];
            f32x4 d = {0.f, 0.f, 0.f, 0.f};
            d = MFMA16(aq0, b0, d);
            d = MFMA16(aq1, b1, d);
#pragma unroll
            for (int reg = 0; reg < 4; ++reg)
                Pw[(quad * 4 + reg) * 72 + ns * 16 + l15] = (f16)d[reg];
        }
        aqp[r][0] = *(const f16x8*)&Pw[l15 * 72 + quad * 8];
        aqp[r][1] = *(const f16x8*)&Pw[l15 * 72 + quad * 8 + 32];
    }

    f16x8 ones;
#pragma unroll
    for (int u = 0; u < 8; ++u) ones[u] = (f16)1.0f;

    f32x4 o[4] = {{0,0,0,0},{0,0,0,0},{0,0,0,0},{0,0,0,0}};
    f32x4 lacc = {0.f, 0.f, 0.f, 0.f};
    float mrun[4] = {-1e30f, -1e30f, -1e30f, -1e30f};

    const unsigned char* adjrow =
        adjp + (size_t)(b * 512 + (wi0 >> 2) + quad) * (S_ * 4);
    const float* maskrow = mask + (size_t)b * S_;
    const f16* vtb = vt + (size_t)bn * DH * S_;

    // ---- named K/V fragment sets (single-set prefetch, WAR overwrite) ----
    f16x8 kb0a, kb0b, kb1a, kb1b, kb2a, kb2b, kb3a, kb3b;
    f16x8 vb0a, vb0b, vb1a, vb1b, vb2a, vb2b, vb3a, vb3b;

#define LOAD_KB(T) do {                                                      \
    const f16* kp_ = k + kbase + (size_t)((T) * 64 + l15) * DH + quad * 8;   \
    kb0a = *(const f16x8*)(kp_);                                             \
    kb0b = *(const f16x8*)(kp_ + 32);                                        \
    kb1a = *(const f16x8*)(kp_ + 16 * DH);                                   \
    kb1b = *(const f16x8*)(kp_ + 16 * DH + 32);                              \
    kb2a = *(const f16x8*)(kp_ + 32 * DH);                                   \
    kb2b = *(const f16x8*)(kp_ + 32 * DH + 32);                              \
    kb3a = *(const f16x8*)(kp_ + 48 * DH);                                   \
    kb3b = *(const f16x8*)(kp_ + 48 * DH + 32);                              \
} while (0)

#define LOAD_VB(T) do {                                                      \
    const f16* vp_ = vtb + (size_t)l15 * S_ + (T) * 64 + quad * 8;           \
    vb0a = *(const f16x8*)(vp_);                                             \
    vb0b = *(const f16x8*)(vp_ + 32);                                        \
    vb1a = *(const f16x8*)(vp_ + 16 * S_);                                   \
    vb1b = *(const f16x8*)(vp_ + 16 * S_ + 32);                              \
    vb2a = *(const f16x8*)(vp_ + 32 * S_);                                   \
    vb2b = *(const f16x8*)(vp_ + 32 * S_ + 32);                              \
    vb3a = *(const f16x8*)(vp_ + 48 * S_);                                   \
    vb3b = *(const f16x8*)(vp_ + 48 * S_ + 32);                              \
} while (0)

// scores for one 16-col group from pre-loaded K frags (round-3 math)
#define SCORE1(T, JS, KA, KB_, O0, O1, O2, O3) do {                          \
    const int jcol_ = (T) * 64 + (JS) * 16 + l15;                            \
    f32x4 aqk_ = {0.f, 0.f, 0.f, 0.f};                                       \
    aqk_ = MFMA16(aq0, KA, aqk_);                                            \
    aqk_ = MFMA16(aq1, KB_, aqk_);                                           \
    uchar4 a4_ = *(const uchar4*)(adjrow + (size_t)jcol_ * 4);               \
    unsigned int c0_ = a4_.x, c1_ = a4_.y, c2_ = a4_.z, c3_ = a4_.w;         \
    float mkL_ = maskrow[jcol_] * L2E;                                       \
    float t0_ = aqk_[0], t1_ = aqk_[1], t2_ = aqk_[2], t3_ = aqk_[3];        \
    _Pragma("unroll")                                                        \
    for (int r = 0; r < RD; ++r) {                                           \
        f32x4 z_ = {0.f, 0.f, 0.f, 0.f};                                     \
        z_ = MFMA16(aqp[r][0], KA, z_);                                      \
        z_ = MFMA16(aqp[r][1], KB_, z_);                                     \
        t0_ = fmaf((float)((c0_ >> r) & 1u), z_[0], t0_);                    \
        t1_ = fmaf((float)((c1_ >> r) & 1u), z_[1], t1_);                    \
        t2_ = fmaf((float)((c2_ >> r) & 1u), z_[2], t2_);                    \
        t3_ = fmaf((float)((c3_ >> r) & 1u), z_[3], t3_);                    \
    }                                                                        \
    O0 = fmaf(t0_, SCL, lut[c0_] + mkL_);                                    \
    O1 = fmaf(t1_, SCL, lut[c1_] + mkL_);                                    \
    O2 = fmaf(t2_, SCL, lut[c2_] + mkL_);                                    \
    O3 = fmaf(t3_, SCL, lut[c3_] + mkL_);                                    \
} while (0)

    LOAD_KB(0);

#pragma unroll 2
    for (int t = 0; t < 32; ++t) {
        const int j0 = t * 64;

        // V frags for THIS tile: latency hides under the 48 SCORES MFMAs
        LOAD_VB(t);

        float sc[4][4];
        SCORE1(t, 0, kb0a, kb0b, sc[0][0], sc[0][1], sc[0][2], sc[0][3]);
        SCORE1(t, 1, kb1a, kb1b, sc[1][0], sc[1][1], sc[1][2], sc[1][3]);
        SCORE1(t, 2, kb2a, kb2b, sc[2][0], sc[2][1], sc[2][2], sc[2][3]);
        SCORE1(t, 3, kb3a, kb3b, sc[3][0], sc[3][1], sc[3][2], sc[3][3]);

        // K frags for NEXT tile: kb dead after SCORES; latency hides under
        // softmax + PV.  Last iteration clamps (harmless re-load of t=31).
        {
            int tn = t + 1;
            if (tn > 31) tn = 31;
            LOAD_KB(tn);
        }

        // ---- online softmax (exp2 domain; rows in 16-lane groups) ----
        float alpha[4];
#pragma unroll
        for (int reg = 0; reg < 4; ++reg) {
            float nm = fmaxf(fmaxf(sc[0][reg], sc[1][reg]),
                             fmaxf(sc[2][reg], sc[3][reg]));
#pragma unroll
            for (int off = 1; off < 16; off <<= 1)
                nm = fmaxf(nm, __shfl_xor(nm, off));
            float mn = fmaxf(mrun[reg], nm);
            alpha[reg] = exp2fast(mrun[reg] - mn);
            mrun[reg] = mn;
        }
#pragma unroll
        for (int js = 0; js < 4; ++js)
#pragma unroll
            for (int reg = 0; reg < 4; ++reg) {
                float p = exp2fast(sc[js][reg] - mrun[reg]);
                Pw[(quad * 4 + reg) * 72 + js * 16 + l15] = (f16)p;
            }
#pragma unroll
        for (int reg = 0; reg < 4; ++reg) {
            lacc[reg] *= alpha[reg];
#pragma unroll
            for (int ds = 0; ds < 4; ++ds) o[ds][reg] *= alpha[reg];
        }

        // ---- PV + row-sum via MFMA (V already in registers) ----
        f16x8 pa0 = *(const f16x8*)&Pw[l15 * 72 + quad * 8];
        f16x8 pa1 = *(const f16x8*)&Pw[l15 * 72 + quad * 8 + 32];
        lacc = MFMA16(pa0, ones, lacc);
        lacc = MFMA16(pa1, ones, lacc);
        o[0] = MFMA16(pa0, vb0a, o[0]);
        o[0] = MFMA16(pa1, vb0b, o[0]);
        o[1] = MFMA16(pa0, vb1a, o[1]);
        o[1] = MFMA16(pa1, vb1b, o[1]);
        o[2] = MFMA16(pa0, vb2a, o[2]);
        o[2] = MFMA16(pa1, vb2b, o[2]);
        o[3] = MFMA16(pa0, vb3a, o[3]);
        o[3] = MFMA16(pa1, vb3b, o[3]);
    }

#undef SCORE1
#undef LOAD_KB
#undef LOAD_VB

    // ---- epilogue ----
#pragma unroll
    for (int reg = 0; reg < 4; ++reg) {
        float inv = 1.f / lacc[reg];
        int i = wi0 + quad * 4 + reg;
#pragma unroll
        for (int ds = 0; ds < 4; ++ds)
            out[((size_t)b * S_ + i) * H_ + n * DH + ds * 16 + l15] =
                o[ds][reg] * inv;
    }
}

// ---------------------------------------------------------------------------
extern "C" void kernel_launch(void* const* d_in, const int* in_sizes, int n_in,
                              void* d_out, int out_size, void* d_ws, size_t ws_size,
                              hipStream_t stream)
{
    const float* hs   = (const float*)d_in[0];
    const float* mask = (const float*)d_in[1];
    const float* adj  = (const float*)d_in[2];
    const float* Wq   = (const float*)d_in[3];
    const float* bq   = (const float*)d_in[4];
    const float* Wk   = (const float*)d_in[5];
    const float* bk   = (const float*)d_in[6];
    const float* Wv   = (const float*)d_in[7];
    const float* bv   = (const float*)d_in[8];
    const float* bili = (const float*)d_in[9];
    const float* absb = (const float*)d_in[10];
    float* out = (float*)d_out;

    const size_t QKV = (size_t)BN * S_ * DH;       // 3.1M elems
    f16* q  = (f16*)d_ws;
    f16* k  = q + QKV;
    f16* vt = k + QKV;
    unsigned char* adjp = (unsigned char*)(vt + QKV);       // 8 MB

    qkv_pack<<<768 + 2048, 256, 0, stream>>>(hs, Wq, Wk, Wv, bq, bk, bv,
                                             q, k, vt, adj, adjp);
    attn<<<768, 256, 0, stream>>>(q, k, vt, bili, adjp, mask, absb, out);
}

// Round 15
// 478.080 us; speedup vs baseline: 1.1228x; 1.1228x over previous
//
#include <hip/hip_runtime.h>
#include <cstdint>
#include <cstddef>

#define B_  2
#define S_  2048
#define H_  768
#define NH  12
#define DH  64
#define RD  5
#define BN  (B_*NH)   // 24

typedef _Float16 f16;
typedef __attribute__((ext_vector_type(8))) _Float16 f16x8;
typedef __attribute__((ext_vector_type(4))) float f32x4;

#define MFMA16(a, b, c) __builtin_amdgcn_mfma_f32_16x16x32_f16((a), (b), (c), 0, 0, 0)

#if __has_builtin(__builtin_amdgcn_exp2f)
__device__ __forceinline__ float exp2fast(float x) { return __builtin_amdgcn_exp2f(x); }
#else
__device__ __forceinline__ float exp2fast(float x) { return __expf(0.69314718056f * x); }
#endif

#define SCL 0.1803368801f   /* 0.125 * log2(e) */
#define L2E 1.44269504f

// fp32 -> f16 convert-and-store of 16 contiguous elements.
__device__ __forceinline__ void cvt16(const float* __restrict__ src, f16* dst)
{
    float4 f0 = ((const float4*)src)[0];
    float4 f1 = ((const float4*)src)[1];
    float4 f2 = ((const float4*)src)[2];
    float4 f3 = ((const float4*)src)[3];
    f16 h[16] = {(f16)f0.x, (f16)f0.y, (f16)f0.z, (f16)f0.w,
                 (f16)f1.x, (f16)f1.y, (f16)f1.z, (f16)f1.w,
                 (f16)f2.x, (f16)f2.y, (f16)f2.z, (f16)f2.w,
                 (f16)f3.x, (f16)f3.y, (f16)f3.z, (f16)f3.w};
    *(f16x8*)dst       = *(const f16x8*)&h[0];
    *(f16x8*)(dst + 8) = *(const f16x8*)&h[8];
}

// ---------------------------------------------------------------------------
// Kernel 1 (FUSED): qkv_gemm (fp32 inputs, in-staging f16 convert) + adjpack.
// Verified rounds 9/13: 480 us pipeline.
// ---------------------------------------------------------------------------
__global__ __launch_bounds__(256, 3) void qkv_pack(
    const float* __restrict__ hs,
    const float* __restrict__ Wq, const float* __restrict__ Wk,
    const float* __restrict__ Wv,
    const float* __restrict__ bq, const float* __restrict__ bk,
    const float* __restrict__ bv,
    f16* __restrict__ qo, f16* __restrict__ ko, f16* __restrict__ vt,
    const float* __restrict__ adj, unsigned char* __restrict__ adjp)
{
    __shared__ __align__(16) f16 Xs[64][72];
    __shared__ __align__(16) f16 Ws[3][64][72];

    const int tid = threadIdx.x;

    if (blockIdx.x >= 768) {
        const int idx4 = (blockIdx.x - 768) * 256 + tid;   // [0, 2^19)
        const int j4 = idx4 & 511;
        const int iq = (idx4 >> 9) & 511;
        const int b  = idx4 >> 18;
        unsigned int wbits[4] = {0, 0, 0, 0};
#pragma unroll
        for (int r = 0; r < RD; ++r) {
#pragma unroll
            for (int ii = 0; ii < 4; ++ii) {
                float4 v = *(const float4*)(adj +
                    (((size_t)(r * B_ + b) * S_) + iq * 4 + ii) * S_ + j4 * 4);
                float vv[4] = {v.x, v.y, v.z, v.w};
#pragma unroll
                for (int jj = 0; jj < 4; ++jj)
                    wbits[jj] |= (vv[jj] != 0.f ? 1u : 0u) << (r + 8 * ii);
            }
        }
        uint4 pk = {wbits[0], wbits[1], wbits[2], wbits[3]};
        *(uint4*)(adjp + ((size_t)(b * 512 + iq) * S_ + j4 * 4) * 4) = pk;
        return;
    }

    const int n  = blockIdx.x % 12;
    const int m0 = (blockIdx.x / 12) * 64;
    const int w = tid >> 6, lane = tid & 63;
    const int l15 = lane & 15, quad = lane >> 4;
    const int srow = tid >> 2, sc0 = (tid & 3) * 16;

    f32x4 acc[3][4];
#pragma unroll
    for (int i = 0; i < 3; ++i)
#pragma unroll
        for (int ns = 0; ns < 4; ++ns) acc[i][ns] = (f32x4){0.f, 0.f, 0.f, 0.f};

    const float* xsrc = hs + (size_t)(m0 + srow) * H_ + sc0;
    const float* w0src = Wq + (size_t)(n * 64 + srow) * H_ + sc0;
    const float* w1src = Wk + (size_t)(n * 64 + srow) * H_ + sc0;
    const float* w2src = Wv + (size_t)(n * 64 + srow) * H_ + sc0;

    for (int kc = 0; kc < 12; ++kc) {
        __syncthreads();
        cvt16(xsrc  + kc * 64, &Xs[srow][sc0]);
        cvt16(w0src + kc * 64, &Ws[0][srow][sc0]);
        cvt16(w1src + kc * 64, &Ws[1][srow][sc0]);
        cvt16(w2src + kc * 64, &Ws[2][srow][sc0]);
        __syncthreads();

        f16x8 a0 = *(const f16x8*)&Xs[w * 16 + l15][quad * 8];
        f16x8 a1 = *(const f16x8*)&Xs[w * 16 + l15][quad * 8 + 32];
#pragma unroll
        for (int i = 0; i < 3; ++i)
#pragma unroll
            for (int ns = 0; ns < 4; ++ns) {
                f16x8 b0 = *(const f16x8*)&Ws[i][ns * 16 + l15][quad * 8];
                f16x8 b1 = *(const f16x8*)&Ws[i][ns * 16 + l15][quad * 8 + 32];
                acc[i][ns] = MFMA16(a0, b0, acc[i][ns]);
                acc[i][ns] = MFMA16(a1, b1, acc[i][ns]);
            }
    }
    __syncthreads();

    const float* bias[3] = {bq, bk, bv};
    f16 (*T0)[72] = Xs;      // q
    f16 (*T1)[72] = Ws[0];   // k
    f16 (*T2)[72] = Ws[1];   // v
#pragma unroll
    for (int i = 0; i < 3; ++i) {
        f16 (*T)[72] = (i == 0) ? T0 : (i == 1) ? T1 : T2;
#pragma unroll
        for (int ns = 0; ns < 4; ++ns) {
            float bb = bias[i][n * 64 + ns * 16 + l15];
#pragma unroll
            for (int reg = 0; reg < 4; ++reg)
                T[w * 16 + quad * 4 + reg][ns * 16 + l15] =
                    (f16)(acc[i][ns][reg] + bb);
        }
    }
    __syncthreads();

    const int mrow = m0 + srow;
    const int bb2 = mrow >> 11, ss = mrow & 2047;
    {
        f16* dst = qo + ((size_t)(bb2 * NH + n) * S_ + ss) * DH + sc0;
        *(f16x8*)dst       = *(const f16x8*)&T0[srow][sc0];
        *(f16x8*)(dst + 8) = *(const f16x8*)&T0[srow][sc0 + 8];
    }
    {
        f16* dst = ko + ((size_t)(bb2 * NH + n) * S_ + ss) * DH + sc0;
        *(f16x8*)dst       = *(const f16x8*)&T1[srow][sc0];
        *(f16x8*)(dst + 8) = *(const f16x8*)&T1[srow][sc0 + 8];
    }
    {
        f16 tmp[16];
#pragma unroll
        for (int u = 0; u < 16; ++u) tmp[u] = T2[sc0 + u][srow];
        f16* dst = vt + ((size_t)(bb2 * NH + n) * DH + srow) * S_ + (m0 & 2047) + sc0;
        *(f16x8*)dst       = *(const f16x8*)&tmp[0];
        *(f16x8*)(dst + 8) = *(const f16x8*)&tmp[8];
    }
}

// ---------------------------------------------------------------------------
// Kernel 2: MFMA flash attention -- round-13 verified body (215 us, session
// best).  Design record (14 rounds of hardware evidence):
//  - 4-wave blocks, full j-range, 768 blocks: 3 waves/SIMD is the structural
//    floor (the ~160-unified-reg working set; every smaller budget demotes
//    to scratch -- rounds 1/4/5/8/11/14).
//  - K/V single-set register prefetch: +3% (round 7), the only ILP lever
//    that fits the register budget.
//  - Full softmax every tile (defer-max's conditional state write demotes,
//    round 8); no setprio (fences break compiler interleave, -18%, round
//    12); unroll 1 (unroll 2 spills 225 MB, round 14); no block-level
//    j-split (overhead > gain, rounds 2/10).
// ---------------------------------------------------------------------------
__global__ __launch_bounds__(256, 3) void attn(
    const f16* __restrict__ q, const f16* __restrict__ k, const f16* __restrict__ vt,
    const float* __restrict__ bili, const unsigned char* __restrict__ adjp,
    const float* __restrict__ mask, const float* __restrict__ absb,
    float* __restrict__ out)
{
    __shared__ __align__(16) char smem[9216 + 9216 + 128];
    f16*   Mt  = (f16*)smem;                    // [64][72] (prologue only)
    f16*   Pb  = (f16*)(smem + 9216);           // [4][16][72]
    float* lut = (float*)(smem + 9216 + 9216);  // [32]

    const int tid = threadIdx.x;
    const int idx = blockIdx.x;
    const int g = idx & 7;
    const int it = (idx >> 3) & 31;
    const int bn = 8 * (idx >> 8) + g;
    const int b = bn / NH, n = bn % NH;
    const int w = tid >> 6, lane = tid & 63;
    const int l15 = lane & 15, quad = lane >> 4;
    const int wi0 = it * 64 + w * 16;
    const size_t kbase = (size_t)bn * S_ * DH;

    if (tid < 32) {
        float a = 0.f;
#pragma unroll
        for (int r = 0; r < RD; ++r)
            if (tid & (1 << r)) a += absb[r * NH + n];
        lut[tid] = a * SCL;
    }

    const f16* qrow = q + kbase + (size_t)(wi0 + l15) * DH + quad * 8;
    f16x8 aq0 = *(const f16x8*)(qrow);
    f16x8 aq1 = *(const f16x8*)(qrow + 32);

    f16* Pw = Pb + w * 16 * 72;

    // ---- build Q'_r A-frags via MFMA (M_r staged transposed in LDS) ----
    f16x8 aqp[RD][2];
#pragma unroll
    for (int r = 0; r < RD; ++r) {
        __syncthreads();
        {
            int p = tid >> 2, q0 = (tid & 3) * 16;
            const float* src = bili + ((size_t)(r * NH + n) * DH + p) * DH + q0;
            float4 g0 = ((const float4*)src)[0];
            float4 g1 = ((const float4*)src)[1];
            float4 g2 = ((const float4*)src)[2];
            float4 g3 = ((const float4*)src)[3];
            float mv[16] = {g0.x, g0.y, g0.z, g0.w, g1.x, g1.y, g1.z, g1.w,
                            g2.x, g2.y, g2.z, g2.w, g3.x, g3.y, g3.z, g3.w};
#pragma unroll
            for (int u = 0; u < 16; ++u) Mt[(q0 + u) * 72 + p] = (f16)mv[u];
        }
        __syncthreads();
#pragma unroll
        for (int ns = 0; ns < 4; ++ns) {
            f16x8 b0 = *(const f16x8*)&Mt[(ns * 16 + l15) * 72 + quad * 8];
            f16x8 b1 = *(const f16x8*)&Mt[(ns * 16 + l15) * 72 + quad * 8 + 32];
            f32x4 d = {0.f, 0.f, 0.f, 0.f};
            d = MFMA16(aq0, b0, d);
            d = MFMA16(aq1, b1, d);
#pragma unroll
            for (int reg = 0; reg < 4; ++reg)
                Pw[(quad * 4 + reg) * 72 + ns * 16 + l15] = (f16)d[reg];
        }
        aqp[r][0] = *(const f16x8*)&Pw[l15 * 72 + quad * 8];
        aqp[r][1] = *(const f16x8*)&Pw[l15 * 72 + quad * 8 + 32];
    }

    f16x8 ones;
#pragma unroll
    for (int u = 0; u < 8; ++u) ones[u] = (f16)1.0f;

    f32x4 o[4] = {{0,0,0,0},{0,0,0,0},{0,0,0,0},{0,0,0,0}};
    f32x4 lacc = {0.f, 0.f, 0.f, 0.f};
    float mrun[4] = {-1e30f, -1e30f, -1e30f, -1e30f};

    const unsigned char* adjrow =
        adjp + (size_t)(b * 512 + (wi0 >> 2) + quad) * (S_ * 4);
    const float* maskrow = mask + (size_t)b * S_;
    const f16* vtb = vt + (size_t)bn * DH * S_;

    // ---- named K/V fragment sets (single-set prefetch, WAR overwrite) ----
    f16x8 kb0a, kb0b, kb1a, kb1b, kb2a, kb2b, kb3a, kb3b;
    f16x8 vb0a, vb0b, vb1a, vb1b, vb2a, vb2b, vb3a, vb3b;

#define LOAD_KB(T) do {                                                      \
    const f16* kp_ = k + kbase + (size_t)((T) * 64 + l15) * DH + quad * 8;   \
    kb0a = *(const f16x8*)(kp_);                                             \
    kb0b = *(const f16x8*)(kp_ + 32);                                        \
    kb1a = *(const f16x8*)(kp_ + 16 * DH);                                   \
    kb1b = *(const f16x8*)(kp_ + 16 * DH + 32);                              \
    kb2a = *(const f16x8*)(kp_ + 32 * DH);                                   \
    kb2b = *(const f16x8*)(kp_ + 32 * DH + 32);                              \
    kb3a = *(const f16x8*)(kp_ + 48 * DH);                                   \
    kb3b = *(const f16x8*)(kp_ + 48 * DH + 32);                              \
} while (0)

#define LOAD_VB(T) do {                                                      \
    const f16* vp_ = vtb + (size_t)l15 * S_ + (T) * 64 + quad * 8;           \
    vb0a = *(const f16x8*)(vp_);                                             \
    vb0b = *(const f16x8*)(vp_ + 32);                                        \
    vb1a = *(const f16x8*)(vp_ + 16 * S_);                                   \
    vb1b = *(const f16x8*)(vp_ + 16 * S_ + 32);                              \
    vb2a = *(const f16x8*)(vp_ + 32 * S_);                                   \
    vb2b = *(const f16x8*)(vp_ + 32 * S_ + 32);                              \
    vb3a = *(const f16x8*)(vp_ + 48 * S_);                                   \
    vb3b = *(const f16x8*)(vp_ + 48 * S_ + 32);                              \
} while (0)

// scores for one 16-col group from pre-loaded K frags (round-3 math)
#define SCORE1(T, JS, KA, KB_, O0, O1, O2, O3) do {                          \
    const int jcol_ = (T) * 64 + (JS) * 16 + l15;                            \
    f32x4 aqk_ = {0.f, 0.f, 0.f, 0.f};                                       \
    aqk_ = MFMA16(aq0, KA, aqk_);                                            \
    aqk_ = MFMA16(aq1, KB_, aqk_);                                           \
    uchar4 a4_ = *(const uchar4*)(adjrow + (size_t)jcol_ * 4);               \
    unsigned int c0_ = a4_.x, c1_ = a4_.y, c2_ = a4_.z, c3_ = a4_.w;         \
    float mkL_ = maskrow[jcol_] * L2E;                                       \
    float t0_ = aqk_[0], t1_ = aqk_[1], t2_ = aqk_[2], t3_ = aqk_[3];        \
    _Pragma("unroll")                                                        \
    for (int r = 0; r < RD; ++r) {                                           \
        f32x4 z_ = {0.f, 0.f, 0.f, 0.f};                                     \
        z_ = MFMA16(aqp[r][0], KA, z_);                                      \
        z_ = MFMA16(aqp[r][1], KB_, z_);                                     \
        t0_ = fmaf((float)((c0_ >> r) & 1u), z_[0], t0_);                    \
        t1_ = fmaf((float)((c1_ >> r) & 1u), z_[1], t1_);                    \
        t2_ = fmaf((float)((c2_ >> r) & 1u), z_[2], t2_);                    \
        t3_ = fmaf((float)((c3_ >> r) & 1u), z_[3], t3_);                    \
    }                                                                        \
    O0 = fmaf(t0_, SCL, lut[c0_] + mkL_);                                    \
    O1 = fmaf(t1_, SCL, lut[c1_] + mkL_);                                    \
    O2 = fmaf(t2_, SCL, lut[c2_] + mkL_);                                    \
    O3 = fmaf(t3_, SCL, lut[c3_] + mkL_);                                    \
} while (0)

    LOAD_KB(0);

#pragma unroll 1
    for (int t = 0; t < 32; ++t) {
        const int j0 = t * 64;

        // V frags for THIS tile: latency hides under the 48 SCORES MFMAs
        LOAD_VB(t);

        float sc[4][4];
        SCORE1(t, 0, kb0a, kb0b, sc[0][0], sc[0][1], sc[0][2], sc[0][3]);
        SCORE1(t, 1, kb1a, kb1b, sc[1][0], sc[1][1], sc[1][2], sc[1][3]);
        SCORE1(t, 2, kb2a, kb2b, sc[2][0], sc[2][1], sc[2][2], sc[2][3]);
        SCORE1(t, 3, kb3a, kb3b, sc[3][0], sc[3][1], sc[3][2], sc[3][3]);

        // K frags for NEXT tile: kb dead after SCORES; latency hides under
        // softmax + PV.  Last iteration clamps (harmless re-load of t=31).
        {
            int tn = t + 1;
            if (tn > 31) tn = 31;
            LOAD_KB(tn);
        }

        // ---- online softmax (exp2 domain; rows in 16-lane groups) ----
        float alpha[4];
#pragma unroll
        for (int reg = 0; reg < 4; ++reg) {
            float nm = fmaxf(fmaxf(sc[0][reg], sc[1][reg]),
                             fmaxf(sc[2][reg], sc[3][reg]));
#pragma unroll
            for (int off = 1; off < 16; off <<= 1)
                nm = fmaxf(nm, __shfl_xor(nm, off));
            float mn = fmaxf(mrun[reg], nm);
            alpha[reg] = exp2fast(mrun[reg] - mn);
            mrun[reg] = mn;
        }
#pragma unroll
        for (int js = 0; js < 4; ++js)
#pragma unroll
            for (int reg = 0; reg < 4; ++reg) {
                float p = exp2fast(sc[js][reg] - mrun[reg]);
                Pw[(quad * 4 + reg) * 72 + js * 16 + l15] = (f16)p;
            }
#pragma unroll
        for (int reg = 0; reg < 4; ++reg) {
            lacc[reg] *= alpha[reg];
#pragma unroll
            for (int ds = 0; ds < 4; ++ds) o[ds][reg] *= alpha[reg];
        }

        // ---- PV + row-sum via MFMA (V already in registers) ----
        f16x8 pa0 = *(const f16x8*)&Pw[l15 * 72 + quad * 8];
        f16x8 pa1 = *(const f16x8*)&Pw[l15 * 72 + quad * 8 + 32];
        lacc = MFMA16(pa0, ones, lacc);
        lacc = MFMA16(pa1, ones, lacc);
        o[0] = MFMA16(pa0, vb0a, o[0]);
        o[0] = MFMA16(pa1, vb0b, o[0]);
        o[1] = MFMA16(pa0, vb1a, o[1]);
        o[1] = MFMA16(pa1, vb1b, o[1]);
        o[2] = MFMA16(pa0, vb2a, o[2]);
        o[2] = MFMA16(pa1, vb2b, o[2]);
        o[3] = MFMA16(pa0, vb3a, o[3]);
        o[3] = MFMA16(pa1, vb3b, o[3]);
    }

#undef SCORE1
#undef LOAD_KB
#undef LOAD_VB

    // ---- epilogue ----
#pragma unroll
    for (int reg = 0; reg < 4; ++reg) {
        float inv = 1.f / lacc[reg];
        int i = wi0 + quad * 4 + reg;
#pragma unroll
        for (int ds = 0; ds < 4; ++ds)
            out[((size_t)b * S_ + i) * H_ + n * DH + ds * 16 + l15] =
                o[ds][reg] * inv;
    }
}

// ---------------------------------------------------------------------------
extern "C" void kernel_launch(void* const* d_in, const int* in_sizes, int n_in,
                              void* d_out, int out_size, void* d_ws, size_t ws_size,
                              hipStream_t stream)
{
    const float* hs   = (const float*)d_in[0];
    const float* mask = (const float*)d_in[1];
    const float* adj  = (const float*)d_in[2];
    const float* Wq   = (const float*)d_in[3];
    const float* bq   = (const float*)d_in[4];
    const float* Wk   = (const float*)d_in[5];
    const float* bk   = (const float*)d_in[6];
    const float* Wv   = (const float*)d_in[7];
    const float* bv   = (const float*)d_in[8];
    const float* bili = (const float*)d_in[9];
    const float* absb = (const float*)d_in[10];
    float* out = (float*)d_out;

    const size_t QKV = (size_t)BN * S_ * DH;       // 3.1M elems
    f16* q  = (f16*)d_ws;
    f16* k  = q + QKV;
    f16* vt = k + QKV;
    unsigned char* adjp = (unsigned char*)(vt + QKV);       // 8 MB

    qkv_pack<<<768 + 2048, 256, 0, stream>>>(hs, Wq, Wk, Wv, bq, bk, bv,
                                             q, k, vt, adj, adjp);
    attn<<<768, 256, 0, stream>>>(q, k, vt, bili, adjp, mask, absb, out);
}